// Round 5
// baseline (106.986 us; speedup 1.0000x reference)
//
#include <hip/hip_runtime.h>
#include <math.h>

#define THREADS 256
#define CAP 512
#define HIST_BINS 4096
#define RAW_THRESH 2.5f

__device__ __forceinline__ unsigned orderKey(float f) {
    unsigned u = __float_as_uint(f);
    return (u & 0x80000000u) ? ~u : (u | 0x80000000u);
}

// ws layout, derived identically in every kernel from device-readable nrows.
__device__ __forceinline__ void ws_layout(void* ws, int nrows, int total,
                                          float** svals, int** sidx, int** wsn,
                                          float** prob, int** tok) {
    float* f = (float*)ws;
    *svals = f;
    *sidx  = (int*)(f + (size_t)nrows * CAP);
    *wsn   = *sidx + (size_t)nrows * CAP;
    *prob  = (float*)(*wsn + nrows);
    *tok   = (int*)(*prob + total);
}

#define COLLECT1(x, gi) \
    if ((x) >= RAW_THRESH) { int p = atomicAdd(&s_n, 1); if (p < CAP) { u.a.v[p] = (x); u.a.id[p] = (gi); } }
#define COLLECT4(vv, base) \
    COLLECT1((vv).x, (base)) COLLECT1((vv).y, (base) + 1) \
    COLLECT1((vv).z, (base) + 2) COLLECT1((vv).w, (base) + 3)

// One block per DISTINCT needed logits row (grid-stride over nrows; skip rows
// no candidate references). Collect raw >= RAW_THRESH (superset of top-kk
// whenever count >= kk; exact raw-space histogram fallback otherwise), sort
// descending (idx-asc ties), write sorted (val,idx)+count to ws.
__global__ __launch_bounds__(THREADS, 8) void row_kernel(
    const float* __restrict__ logits,
    const int* __restrict__ rel_idx,
    const int* __restrict__ cuf,
    const int* __restrict__ cuq,
    const int* __restrict__ topk_p,
    int bsz, int total, long long logits_n, void* ws)
{
    __shared__ union {
        struct { float v[CAP]; int id[CAP]; float sv[CAP]; int si[CAP]; } a;  // 8 KB
        int hist[HIST_BINS];                                                  // 16 KB
    } u;
    __shared__ int s_n, s_needed;
    __shared__ unsigned s_T, s_maxkey;

    const int tid = threadIdx.x;
    const int nrows = cuq[bsz];
    const int vocab = (int)(logits_n / (long long)nrows);
    int kk = topk_p[0];
    if (kk > vocab) kk = vocab;

    float* svals; int* sidx; int* wsn; float* prob; int* tok;
    ws_layout(ws, nrows, total, &svals, &sidx, &wsn, &prob, &tok);

    for (int r = blockIdx.x; r < nrows; r += gridDim.x) {
        // batch owning this row
        int lo = 0, hi = bsz;
        while (hi - lo > 1) { int mid = (lo + hi) >> 1; if (r >= cuq[mid]) lo = mid; else hi = mid; }
        const int b = lo;
        const int rel = r - cuq[b];

        if (tid == 0) { s_needed = 0; s_n = 0; }
        __syncthreads();
        const int t0 = cuf[b], cnt = cuf[b + 1] - t0;
        for (int l = tid; l < cnt; l += THREADS)
            if (rel_idx[t0 + l] == rel) s_needed = 1;
        __syncthreads();
        if (!s_needed) continue;

        const float* row = logits + (long long)r * (long long)vocab;
        const float4* row4 = (const float4*)row;
        const int nv4 = vocab >> 2;

        // ---- single streaming pass, 4 float4s per thread per iteration ----
        int i = tid;
        for (; i + 3 * THREADS < nv4; i += 4 * THREADS) {
            float4 v0 = row4[i];
            float4 v1 = row4[i + THREADS];
            float4 v2 = row4[i + 2 * THREADS];
            float4 v3 = row4[i + 3 * THREADS];
            COLLECT4(v0, i << 2)
            COLLECT4(v1, (i + THREADS) << 2)
            COLLECT4(v2, (i + 2 * THREADS) << 2)
            COLLECT4(v3, (i + 3 * THREADS) << 2)
        }
        for (; i < nv4; i += THREADS) {
            float4 v = row4[i];
            COLLECT4(v, i << 2)
        }
        for (int j = (nv4 << 2) + tid; j < vocab; j += THREADS) {
            float x = row[j];
            COLLECT1(x, j)
        }
        __syncthreads();
        int n = s_n;

        if (n < kk || n > CAP) {
            // ---- fallback: exact raw-space histogram threshold ----
            __syncthreads();
            for (int j = tid; j < HIST_BINS; j += THREADS) u.hist[j] = 0;
            if (tid == 0) { s_n = 0; s_maxkey = 0; }
            __syncthreads();
            for (int j = tid; j < vocab; j += THREADS) {
                unsigned k = orderKey(row[j]);
                atomicAdd(&u.hist[k >> 20], 1);
                atomicMax(&s_maxkey, k);
            }
            __syncthreads();
            if (tid == 0) {
                int B = (int)(s_maxkey >> 20);
                int cum = 0;
                while (true) {
                    cum += u.hist[B];
                    if (cum >= kk || B == 0) break;
                    --B;
                }
                s_T = ((unsigned)B) << 20;
            }
            __syncthreads();
            const unsigned Tk = s_T;
            for (int j = tid; j < vocab; j += THREADS) {
                float a = row[j];
                if (orderKey(a) >= Tk) {
                    int p = atomicAdd(&s_n, 1);
                    if (p < CAP) { u.a.v[p] = a; u.a.id[p] = j; }
                }
            }
            __syncthreads();
            n = s_n;
            if (n > CAP) n = CAP;
        }

        // ---- rank-sort (value desc, original index asc) ----
        for (int j = tid; j < n; j += THREADS) {
            float v = u.a.v[j];
            int id = u.a.id[j];
            int rk = 0;
            for (int q = 0; q < n; ++q) {
                float w = u.a.v[q];
                rk += (w > v) || (w == v && u.a.id[q] < id);
            }
            u.a.sv[rk] = v;
            u.a.si[rk] = id;
        }
        __syncthreads();
        for (int j = tid; j < n; j += THREADS) {
            svals[(size_t)r * CAP + j] = u.a.sv[j];
            sidx[(size_t)r * CAP + j]  = u.a.si[j];
        }
        if (tid == 0) wsn[r] = n;
        __syncthreads();   // LDS reused next grid-stride iteration
    }
}

// One wave per candidate token: scale the row's sorted raws by this token's
// temperature, top-k tie count, argmax (min idx among scaled == max), then the
// exact sequential softmax / cumsum / top-p epilogue.
__global__ __launch_bounds__(64) void token_kernel(
    const int* __restrict__ rel_idx,
    const int* __restrict__ cuf,
    const int* __restrict__ cuq,
    const float* __restrict__ temps,
    const int* __restrict__ topk_p,
    const float* __restrict__ topp_p,
    int bsz, int total, long long logits_n, void* ws)
{
    __shared__ float sc[CAP];
    __shared__ float e[CAP];
    __shared__ int si[CAP];
    __shared__ int s_m, s_amax;

    const int t = blockIdx.x;
    const int l = threadIdx.x;
    const int nrows = cuq[bsz];
    const int vocab = (int)(logits_n / (long long)nrows);
    int kk = topk_p[0];
    if (kk > vocab) kk = vocab;

    float* svals; int* sidx; int* wsn; float* prob; int* tok;
    ws_layout(ws, nrows, total, &svals, &sidx, &wsn, &prob, &tok);

    int lo = 0, hi = bsz;
    while (hi - lo > 1) { int mid = (lo + hi) >> 1; if (t >= cuf[mid]) lo = mid; else hi = mid; }
    const int b = lo;
    const int row = cuq[b] + rel_idx[t];
    const float T = temps[t];
    const int n = wsn[row];

    for (int j = l; j < n; j += 64) {
        sc[j] = svals[(size_t)row * CAP + j] / T;
        si[j] = sidx[(size_t)row * CAP + j];
    }
    __syncthreads();
    const float M = sc[0];
    const float thrk = sc[kk - 1];

    int mcnt = 0;
    int cand = 0x7fffffff;
    for (int j = l; j < n; j += 64) {
        mcnt += (sc[j] >= thrk) ? 1 : 0;
        if (sc[j] == M && si[j] < cand) cand = si[j];
    }
    for (int off = 32; off > 0; off >>= 1) {
        mcnt += __shfl_down(mcnt, off);
        int oc = __shfl_down(cand, off);
        if (oc < cand) cand = oc;
    }
    if (l == 0) { s_m = mcnt; s_amax = cand; }
    __syncthreads();
    const int m = s_m;
    for (int j = l; j < m; j += 64) e[j] = expf(sc[j] - M);
    __syncthreads();
    if (l == 0) {
        float Z1 = 0.f;
        for (int j = 0; j < m; ++j) Z1 += e[j];
        const float topp = topp_p[0];
        int jcut = m - 1;
        float c = 0.f;
        for (int j = 0; j < m; ++j) {
            float p = e[j] / Z1;
            c += p;
            if (c > topp) { jcut = j; break; }
        }
        float Z2 = 0.f;
        for (int j = 0; j <= jcut; ++j) Z2 += e[j];
        prob[t] = 1.0f / Z2;
        tok[t] = s_amax;
    }
}

// One wave per batch: stable sort by score desc, filter, write int32 outputs.
__global__ __launch_bounds__(64) void finalize_kernel(
    const int* __restrict__ rel_idx,
    const int* __restrict__ boff,
    const int* __restrict__ cuf,
    const int* __restrict__ cuq,
    const int* __restrict__ num_transfer,
    const float* __restrict__ thresholds,
    int bsz, int total, int L,
    void* ws,
    int* __restrict__ out)
{
    const int bq = blockIdx.x;
    const int l = threadIdx.x;
    const int nrows = cuq[bsz];
    float* svals; int* sidx; int* wsn; float* prob; int* tok;
    ws_layout(ws, nrows, total, &svals, &sidx, &wsn, &prob, &tok);

    const int start = cuf[bq];
    int cnt = cuf[bq + 1] - start;
    if (cnt > L) cnt = L;

    __shared__ float ss[64]; __shared__ int stk[64]; __shared__ int sp[64];
    __shared__ float ss2[64]; __shared__ int stk2[64]; __shared__ int sp2[64];

    float score = -INFINITY; int tk = 0; int pos = 0;
    if (l < L) {
        if (l < cnt) {
            int t = start + l;
            score = prob[t];
            tk = tok[t];
            pos = rel_idx[t] + boff[bq];
        }
        ss[l] = score; stk[l] = tk; sp[l] = pos;
    }
    __syncthreads();
    if (l < L) {
        int r = 0;
        for (int j = 0; j < L; ++j) {
            float w = ss[j];
            r += (w > score) || (w == score && j < l);
        }
        ss2[r] = score; stk2[r] = tk; sp2[r] = pos;
    }
    __syncthreads();

    int k = num_transfer[bq]; if (k < 0) k = 0;
    const float thrb = thresholds[bq];
    bool kp = false;
    if (l < L) {
        float s = ss2[l];
        kp = (l < k) && (s >= thrb) && (s > -INFINITY);
        out[bq * L + l] = kp ? sp2[l] : 0;
        out[bsz * L + bq * L + l] = kp ? stk2[l] : -1;
    }
    unsigned long long mask = __ballot(kp);
    if (l == 0) out[2 * bsz * L + bq] = (int)__popcll(mask);
}

extern "C" void kernel_launch(void* const* d_in, const int* in_sizes, int n_in,
                              void* d_out, int out_size, void* d_ws, size_t ws_size,
                              hipStream_t stream) {
    const float* logits   = (const float*)d_in[0];
    const int*   rel      = (const int*)d_in[1];
    const int*   boff     = (const int*)d_in[2];
    const int*   cuf      = (const int*)d_in[3];
    const int*   cuq      = (const int*)d_in[4];
    const float* temps    = (const float*)d_in[5];
    const int*   ntr      = (const int*)d_in[6];
    const float* thr      = (const float*)d_in[7];
    const float* topp     = (const float*)d_in[8];
    const int*   topk     = (const int*)d_in[9];

    const int total = in_sizes[1];
    const int bsz   = in_sizes[6];
    const long long logits_n = (long long)in_sizes[0];
    const int L = (out_size - bsz) / (2 * bsz);   // block_size

    row_kernel<<<total, THREADS, 0, stream>>>(
        logits, rel, cuf, cuq, topk, bsz, total, logits_n, d_ws);

    token_kernel<<<total, 64, 0, stream>>>(
        rel, cuf, cuq, temps, topk, topp, bsz, total, logits_n, d_ws);

    finalize_kernel<<<bsz, 64, 0, stream>>>(
        rel, boff, cuf, cuq, ntr, thr, bsz, total, L, d_ws, (int*)d_out);
}

// Round 6
// 84.196 us; speedup vs baseline: 1.2707x; 1.2707x over previous
//
#include <hip/hip_runtime.h>
#include <math.h>

#define THREADS 256
#define CAP 512
#define HIST_BINS 4096
#define RAW_THRESH 2.5f

typedef float f32x4 __attribute__((ext_vector_type(4)));

__device__ __forceinline__ unsigned orderKey(float f) {
    unsigned u = __float_as_uint(f);
    return (u & 0x80000000u) ? ~u : (u | 0x80000000u);
}

// ws layout, derived identically in every kernel from device-readable nrows.
struct WS {
    int* mark; int* list; int* cnt;
    float* svals; int* sidx; int* wsn;
    float* prob; int* tok;
};
__device__ __forceinline__ WS ws_layout(void* ws, int nrows, int total) {
    WS w;
    w.mark = (int*)ws;
    w.list = w.mark + nrows;
    w.cnt  = w.list + nrows;
    w.svals = (float*)(w.cnt + 4);
    w.sidx  = (int*)(w.svals + (size_t)nrows * CAP);
    w.wsn   = w.sidx + (size_t)nrows * CAP;
    w.prob  = (float*)(w.wsn + nrows);
    w.tok   = (int*)(w.prob + total);
    return w;
}

// Zero mark[] and the distinct-row counter.
__global__ void setup_kernel(const int* __restrict__ cuq, int bsz, int total, void* ws) {
    const int nrows = cuq[bsz];
    WS w = ws_layout(ws, nrows, total);
    for (int i = blockIdx.x * blockDim.x + threadIdx.x; i < nrows; i += gridDim.x * blockDim.x)
        w.mark[i] = 0;
    if (blockIdx.x == 0 && threadIdx.x == 0) w.cnt[0] = 0;
}

// One thread per candidate: dedup referenced rows into a compact list.
__global__ void mark_kernel(const int* __restrict__ rel_idx,
                            const int* __restrict__ cuf,
                            const int* __restrict__ cuq,
                            int bsz, int total, void* ws) {
    const int t = blockIdx.x * blockDim.x + threadIdx.x;
    if (t >= total) return;
    const int nrows = cuq[bsz];
    WS w = ws_layout(ws, nrows, total);
    int lo = 0, hi = bsz;
    while (hi - lo > 1) { int mid = (lo + hi) >> 1; if (t >= cuf[mid]) lo = mid; else hi = mid; }
    const int row = cuq[lo] + rel_idx[t];
    if (atomicCAS(&w.mark[row], 0, 1) == 0) {
        int p = atomicAdd(w.cnt, 1);
        w.list[p] = row;
    }
}

#define COLLECT1(x, gi) \
    if ((x) >= RAW_THRESH) { int p = atomicAdd(&s_n, 1); if (p < CAP) { u.a.v[p] = (x); u.a.id[p] = (gi); } }
#define COLLECT4(vv, base) \
    COLLECT1((vv).x, (base)) COLLECT1((vv).y, (base) + 1) \
    COLLECT1((vv).z, (base) + 2) COLLECT1((vv).w, (base) + 3)

// One block per DISTINCT needed row (from the compact list). Single NT
// streaming pass collecting raw >= RAW_THRESH (superset of top-kk whenever
// count >= kk; exact raw-space histogram fallback otherwise), rank-sort
// descending (idx-asc ties), write sorted (val,idx)+count to ws.
__global__ __launch_bounds__(THREADS, 8) void row_kernel(
    const float* __restrict__ logits,
    const int* __restrict__ cuq,
    const int* __restrict__ topk_p,
    int bsz, int total, long long logits_n, void* ws)
{
    __shared__ union {
        struct { float v[CAP]; int id[CAP]; float sv[CAP]; int si[CAP]; } a;  // 8 KB
        int hist[HIST_BINS];                                                  // 16 KB
    } u;
    __shared__ int s_n;
    __shared__ unsigned s_T, s_maxkey;

    const int tid = threadIdx.x;
    const int nrows = cuq[bsz];
    const int vocab = (int)(logits_n / (long long)nrows);
    int kk = topk_p[0];
    if (kk > vocab) kk = vocab;

    WS w = ws_layout(ws, nrows, total);
    if (blockIdx.x >= w.cnt[0]) return;
    const int r = w.list[blockIdx.x];

    if (tid == 0) s_n = 0;
    __syncthreads();

    const float* row = logits + (long long)r * (long long)vocab;
    const f32x4* row4 = (const f32x4*)row;
    const int nv4 = vocab >> 2;

    // ---- single streaming pass, 4 nontemporal float4s per thread per iter ----
    int i = tid;
    for (; i + 3 * THREADS < nv4; i += 4 * THREADS) {
        f32x4 v0 = __builtin_nontemporal_load(row4 + i);
        f32x4 v1 = __builtin_nontemporal_load(row4 + i + THREADS);
        f32x4 v2 = __builtin_nontemporal_load(row4 + i + 2 * THREADS);
        f32x4 v3 = __builtin_nontemporal_load(row4 + i + 3 * THREADS);
        COLLECT4(v0, i << 2)
        COLLECT4(v1, (i + THREADS) << 2)
        COLLECT4(v2, (i + 2 * THREADS) << 2)
        COLLECT4(v3, (i + 3 * THREADS) << 2)
    }
    for (; i < nv4; i += THREADS) {
        f32x4 v = __builtin_nontemporal_load(row4 + i);
        COLLECT4(v, i << 2)
    }
    for (int j = (nv4 << 2) + tid; j < vocab; j += THREADS) {
        float x = row[j];
        COLLECT1(x, j)
    }
    __syncthreads();
    int n = s_n;

    if (n < kk || n > CAP) {
        // ---- fallback: exact raw-space histogram threshold ----
        __syncthreads();
        for (int j = tid; j < HIST_BINS; j += THREADS) u.hist[j] = 0;
        if (tid == 0) { s_n = 0; s_maxkey = 0; }
        __syncthreads();
        for (int j = tid; j < vocab; j += THREADS) {
            unsigned k = orderKey(row[j]);
            atomicAdd(&u.hist[k >> 20], 1);
            atomicMax(&s_maxkey, k);
        }
        __syncthreads();
        if (tid == 0) {
            int B = (int)(s_maxkey >> 20);
            int cum = 0;
            while (true) {
                cum += u.hist[B];
                if (cum >= kk || B == 0) break;
                --B;
            }
            s_T = ((unsigned)B) << 20;
        }
        __syncthreads();
        const unsigned Tk = s_T;
        for (int j = tid; j < vocab; j += THREADS) {
            float a = row[j];
            if (orderKey(a) >= Tk) {
                int p = atomicAdd(&s_n, 1);
                if (p < CAP) { u.a.v[p] = a; u.a.id[p] = j; }
            }
        }
        __syncthreads();
        n = s_n;
        if (n > CAP) n = CAP;
    }

    // ---- rank-sort (value desc, original index asc) ----
    for (int j = tid; j < n; j += THREADS) {
        float v = u.a.v[j];
        int id = u.a.id[j];
        int rk = 0;
        for (int q = 0; q < n; ++q) {
            float ww = u.a.v[q];
            rk += (ww > v) || (ww == v && u.a.id[q] < id);
        }
        u.a.sv[rk] = v;
        u.a.si[rk] = id;
    }
    __syncthreads();
    for (int j = tid; j < n; j += THREADS) {
        w.svals[(size_t)r * CAP + j] = u.a.sv[j];
        w.sidx[(size_t)r * CAP + j]  = u.a.si[j];
    }
    if (tid == 0) w.wsn[r] = n;
}

// One wave per candidate token: scale the row's sorted raws by this token's
// temperature, top-k tie count, argmax (min idx among scaled == max), then the
// exact sequential softmax / cumsum / top-p epilogue.
__global__ __launch_bounds__(64) void token_kernel(
    const int* __restrict__ rel_idx,
    const int* __restrict__ cuf,
    const int* __restrict__ cuq,
    const float* __restrict__ temps,
    const int* __restrict__ topk_p,
    const float* __restrict__ topp_p,
    int bsz, int total, long long logits_n, void* ws)
{
    __shared__ float sc[CAP];
    __shared__ float e[CAP];
    __shared__ int si[CAP];
    __shared__ int s_m, s_amax;

    const int t = blockIdx.x;
    const int l = threadIdx.x;
    const int nrows = cuq[bsz];
    const int vocab = (int)(logits_n / (long long)nrows);
    int kk = topk_p[0];
    if (kk > vocab) kk = vocab;

    WS w = ws_layout(ws, nrows, total);

    int lo = 0, hi = bsz;
    while (hi - lo > 1) { int mid = (lo + hi) >> 1; if (t >= cuf[mid]) lo = mid; else hi = mid; }
    const int b = lo;
    const int row = cuq[b] + rel_idx[t];
    const float T = temps[t];
    int n = w.wsn[row];
    if (n > CAP) n = CAP;
    if (kk > n) kk = n;   // safety (never on this data)

    for (int j = l; j < n; j += 64) {
        sc[j] = w.svals[(size_t)row * CAP + j] / T;
        si[j] = w.sidx[(size_t)row * CAP + j];
    }
    __syncthreads();
    const float M = sc[0];
    const float thrk = sc[kk - 1];

    int mcnt = 0;
    int cand = 0x7fffffff;
    for (int j = l; j < n; j += 64) {
        mcnt += (sc[j] >= thrk) ? 1 : 0;
        if (sc[j] == M && si[j] < cand) cand = si[j];
    }
    for (int off = 32; off > 0; off >>= 1) {
        mcnt += __shfl_down(mcnt, off);
        int oc = __shfl_down(cand, off);
        if (oc < cand) cand = oc;
    }
    if (l == 0) { s_m = mcnt; s_amax = cand; }
    __syncthreads();
    const int m = s_m;
    for (int j = l; j < m; j += 64) e[j] = expf(sc[j] - M);
    __syncthreads();
    if (l == 0) {
        float Z1 = 0.f;
        for (int j = 0; j < m; ++j) Z1 += e[j];
        const float topp = topp_p[0];
        int jcut = m - 1;
        float c = 0.f;
        for (int j = 0; j < m; ++j) {
            float p = e[j] / Z1;
            c += p;
            if (c > topp) { jcut = j; break; }
        }
        float Z2 = 0.f;
        for (int j = 0; j <= jcut; ++j) Z2 += e[j];
        w.prob[t] = 1.0f / Z2;
        w.tok[t] = s_amax;
    }
}

// One wave per batch: stable sort by score desc, filter, write int32 outputs.
__global__ __launch_bounds__(64) void finalize_kernel(
    const int* __restrict__ rel_idx,
    const int* __restrict__ boff,
    const int* __restrict__ cuf,
    const int* __restrict__ cuq,
    const int* __restrict__ num_transfer,
    const float* __restrict__ thresholds,
    int bsz, int total, int L,
    void* ws,
    int* __restrict__ out)
{
    const int bq = blockIdx.x;
    const int l = threadIdx.x;
    const int nrows = cuq[bsz];
    WS w = ws_layout(ws, nrows, total);

    const int start = cuf[bq];
    int cnt = cuf[bq + 1] - start;
    if (cnt > L) cnt = L;

    __shared__ float ss[64]; __shared__ int stk[64]; __shared__ int sp[64];
    __shared__ float ss2[64]; __shared__ int stk2[64]; __shared__ int sp2[64];

    float score = -INFINITY; int tk = 0; int pos = 0;
    if (l < L) {
        if (l < cnt) {
            int t = start + l;
            score = w.prob[t];
            tk = w.tok[t];
            pos = rel_idx[t] + boff[bq];
        }
        ss[l] = score; stk[l] = tk; sp[l] = pos;
    }
    __syncthreads();
    if (l < L) {
        int r = 0;
        for (int j = 0; j < L; ++j) {
            float x = ss[j];
            r += (x > score) || (x == score && j < l);
        }
        ss2[r] = score; stk2[r] = tk; sp2[r] = pos;
    }
    __syncthreads();

    int k = num_transfer[bq]; if (k < 0) k = 0;
    const float thrb = thresholds[bq];
    bool kp = false;
    if (l < L) {
        float s = ss2[l];
        kp = (l < k) && (s >= thrb) && (s > -INFINITY);
        out[bq * L + l] = kp ? sp2[l] : 0;
        out[bsz * L + bq * L + l] = kp ? stk2[l] : -1;
    }
    unsigned long long mask = __ballot(kp);
    if (l == 0) out[2 * bsz * L + bq] = (int)__popcll(mask);
}

extern "C" void kernel_launch(void* const* d_in, const int* in_sizes, int n_in,
                              void* d_out, int out_size, void* d_ws, size_t ws_size,
                              hipStream_t stream) {
    const float* logits   = (const float*)d_in[0];
    const int*   rel      = (const int*)d_in[1];
    const int*   boff     = (const int*)d_in[2];
    const int*   cuf      = (const int*)d_in[3];
    const int*   cuq      = (const int*)d_in[4];
    const float* temps    = (const float*)d_in[5];
    const int*   ntr      = (const int*)d_in[6];
    const float* thr      = (const float*)d_in[7];
    const float* topp     = (const float*)d_in[8];
    const int*   topk     = (const int*)d_in[9];

    const int total = in_sizes[1];
    const int bsz   = in_sizes[6];
    const long long logits_n = (long long)in_sizes[0];
    const int L = (out_size - bsz) / (2 * bsz);   // block_size

    setup_kernel<<<64, 256, 0, stream>>>(cuq, bsz, total, d_ws);

    mark_kernel<<<(total + 255) / 256, 256, 0, stream>>>(
        rel, cuf, cuq, bsz, total, d_ws);

    row_kernel<<<total, THREADS, 0, stream>>>(
        logits, cuq, topk, bsz, total, logits_n, d_ws);

    token_kernel<<<total, 64, 0, stream>>>(
        rel, cuf, cuq, temps, topk, topp, bsz, total, logits_n, d_ws);

    finalize_kernel<<<bsz, 64, 0, stream>>>(
        rel, boff, cuf, cuq, ntr, thr, bsz, total, L, d_ws, (int*)d_out);
}